// Round 1
// baseline (3653.170 us; speedup 1.0000x reference)
//
#include <hip/hip_runtime.h>
#include <math.h>

#define NTOT   32768
#define DMODEL 256
#define EDGES  1048576
#define BGRAPH 128
#define NNODE  256
#define NHEAD  8
#define DHEAD  32
#define NLAYER 4
#define DIN    64

__device__ __forceinline__ float bn_scale_c() { return 0.9999950000374997f; } // 1/sqrt(1+1e-5)

// ---------------------------------------------------------------------------
// CSR build (dst-indexed) — run each call; cheap integer work.
// ---------------------------------------------------------------------------
__global__ void k_hist(const int* __restrict__ dst, int* __restrict__ cnt) {
    int e = blockIdx.x * 256 + threadIdx.x;
    if (e < EDGES) atomicAdd(&cnt[dst[e]], 1);
}

__global__ void k_block_sum(const int* __restrict__ cnt, int* __restrict__ bsum) {
    __shared__ int s[256];
    int t = threadIdx.x;
    s[t] = cnt[blockIdx.x * 256 + t];
    __syncthreads();
    for (int o = 128; o > 0; o >>= 1) {
        if (t < o) s[t] += s[t + o];
        __syncthreads();
    }
    if (t == 0) bsum[blockIdx.x] = s[0];
}

__global__ void k_scan_bsum(int* __restrict__ bsum, int nb) {
    if (threadIdx.x == 0) {
        int run = 0;
        for (int i = 0; i < nb; ++i) { int v = bsum[i]; bsum[i] = run; run += v; }
    }
}

__global__ void k_scan_chunks(const int* __restrict__ cnt, const int* __restrict__ bsum,
                              int* __restrict__ rowptr) {
    __shared__ int s[256];
    int t = threadIdx.x;
    int gid = blockIdx.x * 256 + t;
    int v = cnt[gid];
    s[t] = v;
    __syncthreads();
    for (int o = 1; o < 256; o <<= 1) {
        int add = (t >= o) ? s[t - o] : 0;
        __syncthreads();
        s[t] += add;
        __syncthreads();
    }
    int incl = s[t];
    rowptr[gid] = bsum[blockIdx.x] + incl - v;   // exclusive
    if (gid == NTOT - 1) rowptr[NTOT] = bsum[blockIdx.x] + incl;
}

__global__ void k_fill_perm(const int* __restrict__ dst, const int* __restrict__ rowptr,
                            int* __restrict__ cursor, int* __restrict__ perm) {
    int e = blockIdx.x * 256 + threadIdx.x;
    if (e >= EDGES) return;
    int d = dst[e];
    int pos = rowptr[d] + atomicAdd(&cursor[d], 1);
    perm[pos] = e;
}

// ---------------------------------------------------------------------------
// GINE aggregation: z[n,d] = h[n,d] + sum_{e: dst(e)=n} relu(h[src(e),d] + ea(e)*ew[d] + eb[d])
// One block per node, thread = feature dim. Rank-1 edge features (never materialized).
// ---------------------------------------------------------------------------
__global__ __launch_bounds__(256)
void k_gine_agg(const float* __restrict__ h, const float* __restrict__ edge_attr,
                const int* __restrict__ srcs, const int* __restrict__ rowptr,
                const int* __restrict__ perm, const float* __restrict__ ew,
                const float* __restrict__ eb, float* __restrict__ z) {
    __shared__ int   s_src[64];
    __shared__ float s_ea[64];
    int n = blockIdx.x;
    int d = threadIdx.x;
    int beg = rowptr[n], end = rowptr[n + 1];
    float ewd = ew[d], ebd = eb[d];
    float acc = 0.f;
    for (int c = beg; c < end; c += 64) {
        int cnt = min(64, end - c);
        __syncthreads();
        if (d < cnt) {
            int eid = perm[c + d];
            s_src[d] = srcs[eid];
            s_ea[d]  = edge_attr[eid];
        }
        __syncthreads();
        for (int i = 0; i < cnt; ++i) {
            float v = h[(size_t)s_src[i] * DMODEL + d] + s_ea[i] * ewd + ebd;
            acc += fmaxf(v, 0.f);
        }
    }
    size_t o = (size_t)n * DMODEL + d;
    z[o] = h[o] + acc;
}

// ---------------------------------------------------------------------------
// Tiled fp32 GEMM, row-major: C[M,N] = A[M,K] @ B[K,N], fused epilogues.
// MODE 0: +bias    MODE 1: relu(+bias)
// MODE 2: ((+bias)+res)*g*BNS+gb      MODE 3: MODE2 + add2
// BM=BN=64, BK=16, 256 threads, 4x4 per thread. M%64==0, N%64==0, K%16==0.
// ---------------------------------------------------------------------------
template <int MODE>
__global__ __launch_bounds__(256)
void k_gemm(const float* __restrict__ A, const float* __restrict__ B,
            const float* __restrict__ bias, const float* __restrict__ res,
            const float* __restrict__ add2, const float* __restrict__ g,
            const float* __restrict__ gb, float* __restrict__ C,
            int M, int N, int K) {
    const int BM = 64, BN = 64, BK = 16;
    __shared__ float As[BK][BM + 1];
    __shared__ float Bs[BK][BN];

    int bm = blockIdx.y * BM;
    int bn = blockIdx.x * BN;
    int t  = threadIdx.x;
    int tx = t & 15, ty = t >> 4;

    // loaders
    int arow = t >> 2, acol = (t & 3) * 4;          // A: 64 rows x 16 k (float4 along K)
    int brow = t >> 4, bcol = (t & 15) * 4;         // B: 16 k x 64 cols (float4 along N)
    const float* Aptr = A + (size_t)(bm + arow) * K + acol;
    const float* Bptr = B + (size_t)brow * N + bn + bcol;

    float acc[4][4] = {};

    for (int k0 = 0; k0 < K; k0 += BK) {
        float4 av = *(const float4*)(Aptr + k0);
        float4 bv = *(const float4*)(Bptr + (size_t)k0 * N);
        As[acol + 0][arow] = av.x;
        As[acol + 1][arow] = av.y;
        As[acol + 2][arow] = av.z;
        As[acol + 3][arow] = av.w;
        *(float4*)&Bs[brow][bcol] = bv;
        __syncthreads();
#pragma unroll
        for (int k = 0; k < BK; ++k) {
            float a0 = As[k][ty * 4 + 0], a1 = As[k][ty * 4 + 1];
            float a2 = As[k][ty * 4 + 2], a3 = As[k][ty * 4 + 3];
            float b0 = Bs[k][tx * 4 + 0], b1 = Bs[k][tx * 4 + 1];
            float b2 = Bs[k][tx * 4 + 2], b3 = Bs[k][tx * 4 + 3];
            acc[0][0] += a0 * b0; acc[0][1] += a0 * b1; acc[0][2] += a0 * b2; acc[0][3] += a0 * b3;
            acc[1][0] += a1 * b0; acc[1][1] += a1 * b1; acc[1][2] += a1 * b2; acc[1][3] += a1 * b3;
            acc[2][0] += a2 * b0; acc[2][1] += a2 * b1; acc[2][2] += a2 * b2; acc[2][3] += a2 * b3;
            acc[3][0] += a3 * b0; acc[3][1] += a3 * b1; acc[3][2] += a3 * b2; acc[3][3] += a3 * b3;
        }
        __syncthreads();
    }

    int row0 = bm + ty * 4, col0 = bn + tx * 4;
    float biasv[4], gsv[4] = {}, gbv[4] = {};
#pragma unroll
    for (int j = 0; j < 4; ++j) {
        int c = col0 + j;
        biasv[j] = bias[c];
        if (MODE >= 2) { gsv[j] = g[c] * bn_scale_c(); gbv[j] = gb[c]; }
    }
#pragma unroll
    for (int i = 0; i < 4; ++i) {
        size_t r = (size_t)(row0 + i);
#pragma unroll
        for (int j = 0; j < 4; ++j) {
            float v = acc[i][j] + biasv[j];
            if (MODE == 1) v = fmaxf(v, 0.f);
            if (MODE >= 2) v = (v + res[r * N + col0 + j]) * gsv[j] + gbv[j];
            if (MODE == 3) v += add2[r * N + col0 + j];
            C[r * N + col0 + j] = v;
        }
    }
}

// ---------------------------------------------------------------------------
// Per-(graph, head) attention. 256 threads = 256 query rows. K,V staged in LDS.
// qkv layout: [NTOT, 768]; q cols [0,256), k [256,512), v [512,768).
// ---------------------------------------------------------------------------
__global__ __launch_bounds__(256)
void k_attn(const float* __restrict__ qkv, float* __restrict__ o) {
    __shared__ float Ks[NNODE * DHEAD];
    __shared__ float Vs[NNODE * DHEAD];
    int bh = blockIdx.x;
    int b = bh >> 3, head = bh & 7;
    int t = threadIdx.x;
    const float* base = qkv + (size_t)b * NNODE * (3 * DMODEL);
    int koff = DMODEL + head * DHEAD;
    int voff = 2 * DMODEL + head * DHEAD;

    for (int p = t; p < NNODE * DHEAD; p += 256) {
        int j = p >> 5, d = p & 31;
        Ks[p] = base[(size_t)j * (3 * DMODEL) + koff + d];
        Vs[p] = base[(size_t)j * (3 * DMODEL) + voff + d];
    }

    float q[DHEAD];
    const float* qrow = base + (size_t)t * (3 * DMODEL) + head * DHEAD;
    const float scale = 0.17677669529663687f; // 1/sqrt(32)
#pragma unroll
    for (int d = 0; d < DHEAD; ++d) q[d] = qrow[d] * scale;
    __syncthreads();

    float m = -1e30f, lsum = 0.f;
    float oa[DHEAD] = {};
    for (int j = 0; j < NNODE; ++j) {
        float s = 0.f;
        const float* kr = &Ks[j * DHEAD];
#pragma unroll
        for (int d = 0; d < DHEAD; ++d) s += q[d] * kr[d];
        if (s > m) {
            float corr = __expf(m - s);
            lsum *= corr;
#pragma unroll
            for (int d = 0; d < DHEAD; ++d) oa[d] *= corr;
            m = s;
        }
        float p = __expf(s - m);
        lsum += p;
        const float* vr = &Vs[j * DHEAD];
#pragma unroll
        for (int d = 0; d < DHEAD; ++d) oa[d] += p * vr[d];
    }
    float inv = 1.f / lsum;
    float* orow = o + ((size_t)b * NNODE + t) * DMODEL + head * DHEAD;
#pragma unroll
    for (int d = 0; d < DHEAD; ++d) orow[d] = oa[d] * inv;
}

// ---------------------------------------------------------------------------
extern "C" void kernel_launch(void* const* d_in, const int* in_sizes, int n_in,
                              void* d_out, int out_size, void* d_ws, size_t ws_size,
                              hipStream_t stream) {
    const float* x          = (const float*)d_in[0];
    const float* edge_attr  = (const float*)d_in[1];
    const float* node_w     = (const float*)d_in[2];
    const float* node_b     = (const float*)d_in[3];
    const float* edge_w     = (const float*)d_in[4];
    const float* edge_b     = (const float*)d_in[5];
    const float* gine_w1    = (const float*)d_in[6];
    const float* gine_b1    = (const float*)d_in[7];
    const float* gine_w2    = (const float*)d_in[8];
    const float* gine_b2    = (const float*)d_in[9];
    const float* attn_in_w  = (const float*)d_in[10];
    const float* attn_in_b  = (const float*)d_in[11];
    const float* attn_out_w = (const float*)d_in[12];
    const float* attn_out_b = (const float*)d_in[13];
    const float* mlp_w1     = (const float*)d_in[14];
    const float* mlp_b1     = (const float*)d_in[15];
    const float* mlp_w2     = (const float*)d_in[16];
    const float* mlp_b2     = (const float*)d_in[17];
    const float* bn1_g      = (const float*)d_in[18];
    const float* bn1_b      = (const float*)d_in[19];
    const float* bn2_g      = (const float*)d_in[20];
    const float* bn2_b      = (const float*)d_in[21];
    const float* bn3_g      = (const float*)d_in[22];
    const float* bn3_b      = (const float*)d_in[23];
    const int*   edge_index = (const int*)d_in[24];
    // d_in[25] = batch (implicit: node/NNODE), unused

    const int* srcp = edge_index;
    const int* dstp = edge_index + EDGES;

    float* out = (float*)d_out;
    char*  ws  = (char*)d_ws;

    // workspace layout
    size_t off = 0;
    float* hbuf = (float*)(ws + off); off += (size_t)NTOT * DMODEL * 4;       // 33.5 MB
    float* t0   = (float*)(ws + off); off += (size_t)NTOT * 3 * DMODEL * 4;   // 100.7 MB (qkv / hidden256 / comb)
    float* t1   = (float*)(ws + off); off += (size_t)NTOT * 2 * DMODEL * 4;   // 67 MB (z / o / hidden512)
    float* t2   = (float*)(ws + off); off += (size_t)NTOT * DMODEL * 4;       // 33.5 MB (h1)
    int* rowptr = (int*)(ws + off);   off += ((size_t)NTOT + 4) * 4;
    int* perm   = (int*)(ws + off);   off += (size_t)EDGES * 4;
    int* cnt    = (int*)(ws + off);   off += (size_t)NTOT * 4;
    int* bsum   = (int*)(ws + off);   off += 128 * 4;
    (void)ws_size; (void)in_sizes; (void)n_in; (void)out_size;

    // --- CSR build (by dst) ---
    hipMemsetAsync(cnt, 0, (size_t)NTOT * 4, stream);
    k_hist<<<EDGES / 256, 256, 0, stream>>>(dstp, cnt);
    k_block_sum<<<NTOT / 256, 256, 0, stream>>>(cnt, bsum);
    k_scan_bsum<<<1, 64, 0, stream>>>(bsum, NTOT / 256);
    k_scan_chunks<<<NTOT / 256, 256, 0, stream>>>(cnt, bsum, rowptr);
    hipMemsetAsync(cnt, 0, (size_t)NTOT * 4, stream);
    k_fill_perm<<<EDGES / 256, 256, 0, stream>>>(dstp, rowptr, cnt, perm);

    // --- node encoder: h = x @ node_w + node_b ---
    k_gemm<0><<<dim3(DMODEL / 64, NTOT / 64), 256, 0, stream>>>(
        x, node_w, node_b, nullptr, nullptr, nullptr, nullptr, hbuf, NTOT, DMODEL, DIN);

    for (int l = 0; l < NLAYER; ++l) {
        const float* gw1 = gine_w1 + (size_t)l * DMODEL * DMODEL;
        const float* gb1 = gine_b1 + (size_t)l * DMODEL;
        const float* gw2 = gine_w2 + (size_t)l * DMODEL * DMODEL;
        const float* gb2 = gine_b2 + (size_t)l * DMODEL;
        const float* aiw = attn_in_w + (size_t)l * DMODEL * 3 * DMODEL;
        const float* aib = attn_in_b + (size_t)l * 3 * DMODEL;
        const float* aow = attn_out_w + (size_t)l * DMODEL * DMODEL;
        const float* aob = attn_out_b + (size_t)l * DMODEL;
        const float* mw1 = mlp_w1 + (size_t)l * DMODEL * 2 * DMODEL;
        const float* mb1 = mlp_b1 + (size_t)l * 2 * DMODEL;
        const float* mw2 = mlp_w2 + (size_t)l * 2 * DMODEL * DMODEL;
        const float* mb2 = mlp_b2 + (size_t)l * DMODEL;

        // GINE: z = h + agg  (into t1)
        k_gine_agg<<<NTOT, 256, 0, stream>>>(hbuf, edge_attr, srcp, rowptr, perm,
                                             edge_w, edge_b, t1);
        // hidden = relu(z @ w1 + b1) (into t0)
        k_gemm<1><<<dim3(DMODEL / 64, NTOT / 64), 256, 0, stream>>>(
            t1, gw1, gb1, nullptr, nullptr, nullptr, nullptr, t0, NTOT, DMODEL, DMODEL);
        // h1 = bn1(hidden @ w2 + b2 + h) (into t2)
        k_gemm<2><<<dim3(DMODEL / 64, NTOT / 64), 256, 0, stream>>>(
            t0, gw2, gb2, hbuf, nullptr, bn1_g + (size_t)l * DMODEL, bn1_b + (size_t)l * DMODEL,
            t2, NTOT, DMODEL, DMODEL);

        // qkv = h @ attn_in_w + b (into t0, N=768)
        k_gemm<0><<<dim3(3 * DMODEL / 64, NTOT / 64), 256, 0, stream>>>(
            hbuf, aiw, aib, nullptr, nullptr, nullptr, nullptr, t0, NTOT, 3 * DMODEL, DMODEL);
        // attention -> o (into t1)
        k_attn<<<BGRAPH * NHEAD, 256, 0, stream>>>(t0, t1);
        // comb = bn2(o @ attn_out_w + b + h) + h1 (into t0)
        k_gemm<3><<<dim3(DMODEL / 64, NTOT / 64), 256, 0, stream>>>(
            t1, aow, aob, hbuf, t2, bn2_g + (size_t)l * DMODEL, bn2_b + (size_t)l * DMODEL,
            t0, NTOT, DMODEL, DMODEL);

        // hidden = relu(comb @ mlp_w1 + b1) (into t1, N=512)
        k_gemm<1><<<dim3(2 * DMODEL / 64, NTOT / 64), 256, 0, stream>>>(
            t0, mw1, mb1, nullptr, nullptr, nullptr, nullptr, t1, NTOT, 2 * DMODEL, DMODEL);
        // h = bn3(comb + hidden @ mlp_w2 + b2) (into hbuf, or d_out on last layer)
        float* dest = (l == NLAYER - 1) ? out : hbuf;
        k_gemm<2><<<dim3(DMODEL / 64, NTOT / 64), 256, 0, stream>>>(
            t1, mw2, mb2, t0, nullptr, bn3_g + (size_t)l * DMODEL, bn3_b + (size_t)l * DMODEL,
            dest, NTOT, DMODEL, 2 * DMODEL);
    }
}

// Round 2
// 1793.205 us; speedup vs baseline: 2.0372x; 2.0372x over previous
//
#include <hip/hip_runtime.h>
#include <math.h>

#define NTOT   32768
#define DMODEL 256
#define EDGES  1048576
#define BGRAPH 128
#define NNODE  256
#define NHEAD  8
#define DHEAD  32
#define NLAYER 4
#define DIN    64

typedef short bf16x8 __attribute__((ext_vector_type(8)));
typedef float f32x4  __attribute__((ext_vector_type(4)));

__device__ __forceinline__ float bn_scale_c() { return 0.9999950000374997f; } // 1/sqrt(1+1e-5)

__device__ __forceinline__ unsigned short f2b(float f) {
    union { float f; unsigned int u; } v; v.f = f;
    unsigned int r = v.u + 0x7FFFu + ((v.u >> 16) & 1u);  // RNE
    return (unsigned short)(r >> 16);
}
__device__ __forceinline__ float b2f(unsigned short u) {
    union { unsigned int u; float f; } v; v.u = ((unsigned int)u) << 16;
    return v.f;
}

// ---------------------------------------------------------------------------
// CSR build (dst-indexed)
// ---------------------------------------------------------------------------
__global__ void k_hist(const int* __restrict__ dst, int* __restrict__ cnt) {
    int e = blockIdx.x * 256 + threadIdx.x;
    if (e < EDGES) atomicAdd(&cnt[dst[e]], 1);
}

__global__ void k_block_sum(const int* __restrict__ cnt, int* __restrict__ bsum) {
    __shared__ int s[256];
    int t = threadIdx.x;
    s[t] = cnt[blockIdx.x * 256 + t];
    __syncthreads();
    for (int o = 128; o > 0; o >>= 1) {
        if (t < o) s[t] += s[t + o];
        __syncthreads();
    }
    if (t == 0) bsum[blockIdx.x] = s[0];
}

__global__ void k_scan_bsum(int* __restrict__ bsum, int nb) {
    if (threadIdx.x == 0) {
        int run = 0;
        for (int i = 0; i < nb; ++i) { int v = bsum[i]; bsum[i] = run; run += v; }
    }
}

__global__ void k_scan_chunks(const int* __restrict__ cnt, const int* __restrict__ bsum,
                              int* __restrict__ rowptr) {
    __shared__ int s[256];
    int t = threadIdx.x;
    int gid = blockIdx.x * 256 + t;
    int v = cnt[gid];
    s[t] = v;
    __syncthreads();
    for (int o = 1; o < 256; o <<= 1) {
        int add = (t >= o) ? s[t - o] : 0;
        __syncthreads();
        s[t] += add;
        __syncthreads();
    }
    int incl = s[t];
    rowptr[gid] = bsum[blockIdx.x] + incl - v;   // exclusive
    if (gid == NTOT - 1) rowptr[NTOT] = bsum[blockIdx.x] + incl;
}

__global__ void k_fill_perm(const int* __restrict__ dst, const int* __restrict__ rowptr,
                            int* __restrict__ cursor, int* __restrict__ perm) {
    int e = blockIdx.x * 256 + threadIdx.x;
    if (e >= EDGES) return;
    int d = dst[e];
    int pos = rowptr[d] + atomicAdd(&cursor[d], 1);
    perm[pos] = e;
}

// ---------------------------------------------------------------------------
// fp32 -> bf16 elementwise (n % 4 == 0)
// ---------------------------------------------------------------------------
__global__ void k_f2b(const float* __restrict__ s, unsigned short* __restrict__ d, int n) {
    int i = (blockIdx.x * 256 + threadIdx.x) * 4;
    if (i >= n) return;
    float4 v = *(const float4*)(s + i);
    d[i + 0] = f2b(v.x); d[i + 1] = f2b(v.y); d[i + 2] = f2b(v.z); d[i + 3] = f2b(v.w);
}

// ---------------------------------------------------------------------------
// Weight convert + transpose: src[l][k][n] (fp32) -> dst[l][n][k] (bf16)
// grid (N/32, K/32, L), block 256 (32x8)
// ---------------------------------------------------------------------------
__global__ __launch_bounds__(256)
void k_convT(const float* __restrict__ src, unsigned short* __restrict__ dst, int K_, int N_) {
    __shared__ float tile[32][33];
    int l = blockIdx.z;
    int n0 = blockIdx.x * 32, k0 = blockIdx.y * 32;
    const float* s = src + (size_t)l * K_ * N_;
    unsigned short* d = dst + (size_t)l * N_ * K_;
    int tx = threadIdx.x & 31, ty = threadIdx.x >> 5;
#pragma unroll
    for (int i = 0; i < 32; i += 8)
        tile[ty + i][tx] = s[(size_t)(k0 + ty + i) * N_ + n0 + tx];
    __syncthreads();
#pragma unroll
    for (int i = 0; i < 32; i += 8)
        d[(size_t)(n0 + ty + i) * K_ + k0 + tx] = f2b(tile[tx][ty + i]);
}

// ---------------------------------------------------------------------------
// GINE aggregation: zb[n,d] = bf16( hf[n,d] + sum_{e: dst=n} relu(hb[src,d] + ea*ew[d] + eb[d]) )
// ---------------------------------------------------------------------------
__global__ __launch_bounds__(256)
void k_gine_agg(const float* __restrict__ hf, const unsigned short* __restrict__ hb,
                const float* __restrict__ edge_attr,
                const int* __restrict__ srcs, const int* __restrict__ rowptr,
                const int* __restrict__ perm, const float* __restrict__ ew,
                const float* __restrict__ eb, unsigned short* __restrict__ zb) {
    __shared__ int   s_src[64];
    __shared__ float s_ea[64];
    int n = blockIdx.x;
    int d = threadIdx.x;
    int beg = rowptr[n], end = rowptr[n + 1];
    float ewd = ew[d], ebd = eb[d];
    float acc = 0.f;
    for (int c = beg; c < end; c += 64) {
        int cnt = min(64, end - c);
        __syncthreads();
        if (d < cnt) {
            int eid = perm[c + d];
            s_src[d] = srcs[eid];
            s_ea[d]  = edge_attr[eid];
        }
        __syncthreads();
        for (int i = 0; i < cnt; ++i) {
            float v = b2f(hb[(size_t)s_src[i] * DMODEL + d]) + s_ea[i] * ewd + ebd;
            acc += fmaxf(v, 0.f);
        }
    }
    size_t o = (size_t)n * DMODEL + d;
    zb[o] = f2b(hf[o] + acc);
}

// ---------------------------------------------------------------------------
// bf16 MFMA GEMM (m97 structure): C[M,N] = A[M,K] @ B[K,N]
// A: bf16 row-major [M,K]; Bt: bf16 [N,K] (pre-transposed weights).
// 128x128 tile, BK=32, 256 threads = 4 waves (2x2), each wave 64x64 (4x4 frags).
// MODE 0: +bias   1: relu(+bias)   2: ((+bias)+res)*g*BNS+gb   3: MODE2 + add2
// WF32/WB16: write fp32 / bf16 outputs.
// ---------------------------------------------------------------------------
template <int MODE, int WF32, int WB16>
__global__ __launch_bounds__(256)
void k_mm(const unsigned short* __restrict__ A, const unsigned short* __restrict__ Bt,
          const float* __restrict__ bias, const float* __restrict__ res,
          const float* __restrict__ add2, const float* __restrict__ g,
          const float* __restrict__ gb, float* __restrict__ Cf,
          unsigned short* __restrict__ Cb, int M, int N, int K) {
    const int BM = 128, BN = 128, BK = 32;
    __shared__ unsigned short As[BM * BK];   // [row][k], 8 KB
    __shared__ unsigned short Bs[BN * BK];   // [col][k], 8 KB

    int t = threadIdx.x;
    int w = t >> 6, l = t & 63;
    int wr = w >> 1, wc = w & 1;
    int bm = blockIdx.y * BM, bn = blockIdx.x * BN;

    f32x4 acc[4][4] = {};

    int rl = l & 15;
    int kc = l >> 4;

    for (int k0 = 0; k0 < K; k0 += BK) {
        // stage A and Bt: each issue = 256 lanes x 16B = 4 KB; 2 issues each.
#pragma unroll
        for (int i = 0; i < 2; ++i) {
            int slot = i * 256 + t;                  // 16B slot
            int row = slot >> 2, kcc = slot & 3;
            const unsigned short* gp = A + (size_t)(bm + row) * K + k0 + kcc * 8;
            __builtin_amdgcn_global_load_lds(
                (const __attribute__((address_space(1))) void*)gp,
                (__attribute__((address_space(3))) void*)&As[(i * 256 + w * 64) * 8],
                16, 0, 0);
        }
#pragma unroll
        for (int i = 0; i < 2; ++i) {
            int slot = i * 256 + t;
            int row = slot >> 2, kcc = slot & 3;
            const unsigned short* gp = Bt + (size_t)(bn + row) * K + k0 + kcc * 8;
            __builtin_amdgcn_global_load_lds(
                (const __attribute__((address_space(1))) void*)gp,
                (__attribute__((address_space(3))) void*)&Bs[(i * 256 + w * 64) * 8],
                16, 0, 0);
        }
        asm volatile("s_waitcnt vmcnt(0)" ::: "memory");
        __syncthreads();

        bf16x8 av[4], bv[4];
#pragma unroll
        for (int m = 0; m < 4; ++m)
            av[m] = *(const bf16x8*)&As[(wr * 64 + m * 16 + rl) * BK + kc * 8];
#pragma unroll
        for (int n = 0; n < 4; ++n)
            bv[n] = *(const bf16x8*)&Bs[(wc * 64 + n * 16 + rl) * BK + kc * 8];
#pragma unroll
        for (int m = 0; m < 4; ++m)
#pragma unroll
            for (int n = 0; n < 4; ++n)
                acc[m][n] = __builtin_amdgcn_mfma_f32_16x16x32_bf16(av[m], bv[n], acc[m][n], 0, 0, 0);
        __syncthreads();
    }

    // epilogue: lane l, frag (m,n), reg j -> row = wr*64+m*16+(l>>4)*4+j, col = wc*64+n*16+(l&15)
    int rh = l >> 4;
#pragma unroll
    for (int n = 0; n < 4; ++n) {
        int col = bn + wc * 64 + n * 16 + rl;
        float bv_ = bias[col];
        float gs = 0.f, gbv = 0.f;
        if (MODE >= 2) { gs = g[col] * bn_scale_c(); gbv = gb[col]; }
#pragma unroll
        for (int m = 0; m < 4; ++m) {
#pragma unroll
            for (int j = 0; j < 4; ++j) {
                int row = bm + wr * 64 + m * 16 + rh * 4 + j;
                size_t idx = (size_t)row * N + col;
                float v = acc[m][n][j] + bv_;
                if (MODE == 1) v = fmaxf(v, 0.f);
                if (MODE >= 2) v = (v + res[idx]) * gs + gbv;
                if (MODE == 3) v += add2[idx];
                if (WF32) Cf[idx] = v;
                if (WB16) Cb[idx] = f2b(v);
            }
        }
    }
}

// ---------------------------------------------------------------------------
// Per-(graph, head) attention, bf16 in/out, fp32 compute. Chunked branchless
// online softmax (rescale once per 32-key chunk).
// ---------------------------------------------------------------------------
__global__ __launch_bounds__(256)
void k_attn(const unsigned short* __restrict__ qkv, unsigned short* __restrict__ o) {
    __shared__ float Ks[NNODE * DHEAD];
    __shared__ float Vs[NNODE * DHEAD];
    int bh = blockIdx.x;
    int b = bh >> 3, head = bh & 7;
    int t = threadIdx.x;
    const unsigned short* base = qkv + (size_t)b * NNODE * (3 * DMODEL);
    int koff = DMODEL + head * DHEAD;
    int voff = 2 * DMODEL + head * DHEAD;

    for (int p = t; p < NNODE * DHEAD; p += 256) {
        int j = p >> 5, d = p & 31;
        Ks[p] = b2f(base[(size_t)j * (3 * DMODEL) + koff + d]);
        Vs[p] = b2f(base[(size_t)j * (3 * DMODEL) + voff + d]);
    }

    float q[DHEAD];
    const unsigned short* qrow = base + (size_t)t * (3 * DMODEL) + head * DHEAD;
    const float scale = 0.17677669529663687f; // 1/sqrt(32)
#pragma unroll
    for (int d = 0; d < DHEAD; ++d) q[d] = b2f(qrow[d]) * scale;
    __syncthreads();

    float m = -1e30f, lsum = 0.f;
    float oa[DHEAD] = {};
    for (int c0 = 0; c0 < NNODE; c0 += 32) {
        float s[32];
        float mc = -1e30f;
        for (int j = 0; j < 32; ++j) {
            const float* kr = &Ks[(c0 + j) * DHEAD];
            float d0 = 0.f;
#pragma unroll
            for (int d = 0; d < DHEAD; ++d) d0 += q[d] * kr[d];
            s[j] = d0;
            mc = fmaxf(mc, d0);
        }
        float mn = fmaxf(m, mc);
        float corr = __expf(m - mn);
        m = mn;
        lsum *= corr;
#pragma unroll
        for (int d = 0; d < DHEAD; ++d) oa[d] *= corr;
        for (int j = 0; j < 32; ++j) {
            float p = __expf(s[j] - m);
            lsum += p;
            const float* vr = &Vs[(c0 + j) * DHEAD];
#pragma unroll
            for (int d = 0; d < DHEAD; ++d) oa[d] += p * vr[d];
        }
    }
    float inv = 1.f / lsum;
    unsigned short* orow = o + ((size_t)b * NNODE + t) * DMODEL + head * DHEAD;
#pragma unroll
    for (int d = 0; d < DHEAD; ++d) orow[d] = f2b(oa[d] * inv);
}

// ---------------------------------------------------------------------------
extern "C" void kernel_launch(void* const* d_in, const int* in_sizes, int n_in,
                              void* d_out, int out_size, void* d_ws, size_t ws_size,
                              hipStream_t stream) {
    const float* x          = (const float*)d_in[0];
    const float* edge_attr  = (const float*)d_in[1];
    const float* node_w     = (const float*)d_in[2];
    const float* node_b     = (const float*)d_in[3];
    const float* edge_w     = (const float*)d_in[4];
    const float* edge_b     = (const float*)d_in[5];
    const float* gine_w1    = (const float*)d_in[6];
    const float* gine_b1    = (const float*)d_in[7];
    const float* gine_w2    = (const float*)d_in[8];
    const float* gine_b2    = (const float*)d_in[9];
    const float* attn_in_w  = (const float*)d_in[10];
    const float* attn_in_b  = (const float*)d_in[11];
    const float* attn_out_w = (const float*)d_in[12];
    const float* attn_out_b = (const float*)d_in[13];
    const float* mlp_w1     = (const float*)d_in[14];
    const float* mlp_b1     = (const float*)d_in[15];
    const float* mlp_w2     = (const float*)d_in[16];
    const float* mlp_b2     = (const float*)d_in[17];
    const float* bn1_g      = (const float*)d_in[18];
    const float* bn1_b      = (const float*)d_in[19];
    const float* bn2_g      = (const float*)d_in[20];
    const float* bn2_b      = (const float*)d_in[21];
    const float* bn3_g      = (const float*)d_in[22];
    const float* bn3_b      = (const float*)d_in[23];
    const int*   edge_index = (const int*)d_in[24];

    const int* srcp = edge_index;
    const int* dstp = edge_index + EDGES;

    float* out = (float*)d_out;
    char*  ws  = (char*)d_ws;

    // ---- workspace layout ----
    size_t off = 0;
    float* hf    = (float*)(ws + off); off += (size_t)NTOT * DMODEL * 4;      // h fp32
    float* h1f   = (float*)(ws + off); off += (size_t)NTOT * DMODEL * 4;      // h1 fp32
    float* combf = (float*)(ws + off); off += (size_t)NTOT * DMODEL * 4;      // comb fp32
    unsigned short* hb   = (unsigned short*)(ws + off); off += (size_t)NTOT * DMODEL * 2;     // h bf16
    unsigned short* bufA = (unsigned short*)(ws + off); off += (size_t)NTOT * 3 * DMODEL * 2; // z/qkv/comb bf16
    unsigned short* bufB = (unsigned short*)(ws + off); off += (size_t)NTOT * 2 * DMODEL * 2; // hid/o/hid512 bf16
    unsigned short* xb   = (unsigned short*)(ws + off); off += (size_t)NTOT * DIN * 2;
    // weights bf16 [N,K] per family (x L)
    unsigned short* w_node = (unsigned short*)(ws + off); off += (size_t)DMODEL * DIN * 2;
    unsigned short* w_g1   = (unsigned short*)(ws + off); off += (size_t)NLAYER * DMODEL * DMODEL * 2;
    unsigned short* w_g2   = (unsigned short*)(ws + off); off += (size_t)NLAYER * DMODEL * DMODEL * 2;
    unsigned short* w_ai   = (unsigned short*)(ws + off); off += (size_t)NLAYER * 3 * DMODEL * DMODEL * 2;
    unsigned short* w_ao   = (unsigned short*)(ws + off); off += (size_t)NLAYER * DMODEL * DMODEL * 2;
    unsigned short* w_m1   = (unsigned short*)(ws + off); off += (size_t)NLAYER * 2 * DMODEL * DMODEL * 2;
    unsigned short* w_m2   = (unsigned short*)(ws + off); off += (size_t)NLAYER * 2 * DMODEL * DMODEL * 2;
    int* rowptr = (int*)(ws + off); off += ((size_t)NTOT + 4) * 4;
    int* perm   = (int*)(ws + off); off += (size_t)EDGES * 4;
    int* cnt    = (int*)(ws + off); off += (size_t)NTOT * 4;
    int* bsum   = (int*)(ws + off); off += 128 * 4;
    (void)ws_size; (void)in_sizes; (void)n_in; (void)out_size;

    // ---- CSR build ----
    hipMemsetAsync(cnt, 0, (size_t)NTOT * 4, stream);
    k_hist<<<EDGES / 256, 256, 0, stream>>>(dstp, cnt);
    k_block_sum<<<NTOT / 256, 256, 0, stream>>>(cnt, bsum);
    k_scan_bsum<<<1, 64, 0, stream>>>(bsum, NTOT / 256);
    k_scan_chunks<<<NTOT / 256, 256, 0, stream>>>(cnt, bsum, rowptr);
    hipMemsetAsync(cnt, 0, (size_t)NTOT * 4, stream);
    k_fill_perm<<<EDGES / 256, 256, 0, stream>>>(dstp, rowptr, cnt, perm);

    // ---- weight & input conversion ----
    k_f2b<<<NTOT * DIN / 4 / 256, 256, 0, stream>>>(x, xb, NTOT * DIN);
    k_convT<<<dim3(DMODEL / 32, DIN / 32, 1), 256, 0, stream>>>(node_w, w_node, DIN, DMODEL);
    k_convT<<<dim3(DMODEL / 32, DMODEL / 32, NLAYER), 256, 0, stream>>>(gine_w1, w_g1, DMODEL, DMODEL);
    k_convT<<<dim3(DMODEL / 32, DMODEL / 32, NLAYER), 256, 0, stream>>>(gine_w2, w_g2, DMODEL, DMODEL);
    k_convT<<<dim3(3 * DMODEL / 32, DMODEL / 32, NLAYER), 256, 0, stream>>>(attn_in_w, w_ai, DMODEL, 3 * DMODEL);
    k_convT<<<dim3(DMODEL / 32, DMODEL / 32, NLAYER), 256, 0, stream>>>(attn_out_w, w_ao, DMODEL, DMODEL);
    k_convT<<<dim3(2 * DMODEL / 32, DMODEL / 32, NLAYER), 256, 0, stream>>>(mlp_w1, w_m1, DMODEL, 2 * DMODEL);
    k_convT<<<dim3(DMODEL / 32, 2 * DMODEL / 32, NLAYER), 256, 0, stream>>>(mlp_w2, w_m2, 2 * DMODEL, DMODEL);

    // ---- encoder: h = x @ node_w + node_b  (fp32 + bf16) ----
    k_mm<0, 1, 1><<<dim3(DMODEL / 128, NTOT / 128), 256, 0, stream>>>(
        xb, w_node, node_b, nullptr, nullptr, nullptr, nullptr, hf, hb, NTOT, DMODEL, DIN);

    for (int l = 0; l < NLAYER; ++l) {
        const unsigned short* g1 = w_g1 + (size_t)l * DMODEL * DMODEL;
        const unsigned short* g2 = w_g2 + (size_t)l * DMODEL * DMODEL;
        const unsigned short* ai = w_ai + (size_t)l * 3 * DMODEL * DMODEL;
        const unsigned short* ao = w_ao + (size_t)l * DMODEL * DMODEL;
        const unsigned short* m1 = w_m1 + (size_t)l * 2 * DMODEL * DMODEL;
        const unsigned short* m2 = w_m2 + (size_t)l * 2 * DMODEL * DMODEL;

        unsigned short* zb   = bufA;   // [NTOT,256]
        unsigned short* hidb = bufB;   // [NTOT,256]
        unsigned short* qkvb = bufA;   // [NTOT,768]
        unsigned short* ob   = bufB;   // [NTOT,256]
        unsigned short* cmbb = bufA;   // [NTOT,256]
        unsigned short* h5b  = bufB;   // [NTOT,512]

        // GINE aggregate -> zb (bf16)
        k_gine_agg<<<NTOT, 256, 0, stream>>>(hf, hb, edge_attr, srcp, rowptr, perm,
                                             edge_w, edge_b, zb);
        // hidden = relu(z @ w1 + b1) -> hidb
        k_mm<1, 0, 1><<<dim3(2, NTOT / 128), 256, 0, stream>>>(
            zb, g1, gine_b1 + (size_t)l * DMODEL, nullptr, nullptr, nullptr, nullptr,
            nullptr, hidb, NTOT, DMODEL, DMODEL);
        // h1 = bn1(hidden @ w2 + b2 + h) -> h1f (fp32)
        k_mm<2, 1, 0><<<dim3(2, NTOT / 128), 256, 0, stream>>>(
            hidb, g2, gine_b2 + (size_t)l * DMODEL, hf, nullptr,
            bn1_g + (size_t)l * DMODEL, bn1_b + (size_t)l * DMODEL,
            h1f, nullptr, NTOT, DMODEL, DMODEL);

        // qkv = h @ attn_in_w + b -> qkvb (bf16)
        k_mm<0, 0, 1><<<dim3(6, NTOT / 128), 256, 0, stream>>>(
            hb, ai, attn_in_b + (size_t)l * 3 * DMODEL, nullptr, nullptr, nullptr, nullptr,
            nullptr, qkvb, NTOT, 3 * DMODEL, DMODEL);
        // attention -> ob (bf16)
        k_attn<<<BGRAPH * NHEAD, 256, 0, stream>>>(qkvb, ob);
        // comb = bn2(o @ attn_out_w + b + h) + h1 -> combf (fp32) + cmbb (bf16)
        k_mm<3, 1, 1><<<dim3(2, NTOT / 128), 256, 0, stream>>>(
            ob, ao, attn_out_b + (size_t)l * DMODEL, hf, h1f,
            bn2_g + (size_t)l * DMODEL, bn2_b + (size_t)l * DMODEL,
            combf, cmbb, NTOT, DMODEL, DMODEL);

        // hidden512 = relu(comb @ mlp_w1 + b1) -> h5b (bf16)
        k_mm<1, 0, 1><<<dim3(4, NTOT / 128), 256, 0, stream>>>(
            cmbb, m1, mlp_b1 + (size_t)l * 2 * DMODEL, nullptr, nullptr, nullptr, nullptr,
            nullptr, h5b, NTOT, 2 * DMODEL, DMODEL);
        // h = bn3(comb + hidden512 @ mlp_w2 + b2) -> hf (+hb), last layer -> out
        float* dest = (l == NLAYER - 1) ? out : hf;
        k_mm<2, 1, 1><<<dim3(2, NTOT / 128), 256, 0, stream>>>(
            h5b, m2, mlp_b2 + (size_t)l * DMODEL, combf, nullptr,
            bn3_g + (size_t)l * DMODEL, bn3_b + (size_t)l * DMODEL,
            dest, hb, NTOT, DMODEL, 2 * DMODEL);
    }
}

// Round 3
// 1298.962 us; speedup vs baseline: 2.8124x; 1.3805x over previous
//
#include <hip/hip_runtime.h>
#include <math.h>

#define NTOT   32768
#define DMODEL 256
#define EDGES  1048576
#define BGRAPH 128
#define NNODE  256
#define NHEAD  8
#define DHEAD  32
#define NLAYER 4
#define DIN    64

typedef short bf16x8 __attribute__((ext_vector_type(8)));
typedef float f32x4  __attribute__((ext_vector_type(4)));

__device__ __forceinline__ float bn_scale_c() { return 0.9999950000374997f; } // 1/sqrt(1+1e-5)

__device__ __forceinline__ unsigned short f2b(float f) {
    union { float f; unsigned int u; } v; v.f = f;
    unsigned int r = v.u + 0x7FFFu + ((v.u >> 16) & 1u);  // RNE
    return (unsigned short)(r >> 16);
}
__device__ __forceinline__ float b2f(unsigned short u) {
    union { unsigned int u; float f; } v; v.u = ((unsigned int)u) << 16;
    return v.f;
}

// ---------------------------------------------------------------------------
// CSR build (dst-indexed)
// ---------------------------------------------------------------------------
__global__ void k_hist(const int* __restrict__ dst, int* __restrict__ cnt) {
    int e = blockIdx.x * 256 + threadIdx.x;
    if (e < EDGES) atomicAdd(&cnt[dst[e]], 1);
}

__global__ void k_block_sum(const int* __restrict__ cnt, int* __restrict__ bsum) {
    __shared__ int s[256];
    int t = threadIdx.x;
    s[t] = cnt[blockIdx.x * 256 + t];
    __syncthreads();
    for (int o = 128; o > 0; o >>= 1) {
        if (t < o) s[t] += s[t + o];
        __syncthreads();
    }
    if (t == 0) bsum[blockIdx.x] = s[0];
}

__global__ void k_scan_bsum(int* __restrict__ bsum, int nb) {
    if (threadIdx.x == 0) {
        int run = 0;
        for (int i = 0; i < nb; ++i) { int v = bsum[i]; bsum[i] = run; run += v; }
    }
}

__global__ void k_scan_chunks(const int* __restrict__ cnt, const int* __restrict__ bsum,
                              int* __restrict__ rowptr) {
    __shared__ int s[256];
    int t = threadIdx.x;
    int gid = blockIdx.x * 256 + t;
    int v = cnt[gid];
    s[t] = v;
    __syncthreads();
    for (int o = 1; o < 256; o <<= 1) {
        int add = (t >= o) ? s[t - o] : 0;
        __syncthreads();
        s[t] += add;
        __syncthreads();
    }
    int incl = s[t];
    rowptr[gid] = bsum[blockIdx.x] + incl - v;   // exclusive
    if (gid == NTOT - 1) rowptr[NTOT] = bsum[blockIdx.x] + incl;
}

__global__ void k_fill_perm(const int* __restrict__ dst, const int* __restrict__ rowptr,
                            int* __restrict__ cursor, int* __restrict__ perm) {
    int e = blockIdx.x * 256 + threadIdx.x;
    if (e >= EDGES) return;
    int d = dst[e];
    int pos = rowptr[d] + atomicAdd(&cursor[d], 1);
    perm[pos] = e;
}

// ---------------------------------------------------------------------------
// fp32 -> bf16 elementwise (n % 4 == 0)
// ---------------------------------------------------------------------------
__global__ void k_f2b(const float* __restrict__ s, unsigned short* __restrict__ d, int n) {
    int i = (blockIdx.x * 256 + threadIdx.x) * 4;
    if (i >= n) return;
    float4 v = *(const float4*)(s + i);
    d[i + 0] = f2b(v.x); d[i + 1] = f2b(v.y); d[i + 2] = f2b(v.z); d[i + 3] = f2b(v.w);
}

// ---------------------------------------------------------------------------
// Weight convert + transpose: src[l][k][n] (fp32) -> dst[l][n][k] (bf16)
// ---------------------------------------------------------------------------
__global__ __launch_bounds__(256)
void k_convT(const float* __restrict__ src, unsigned short* __restrict__ dst, int K_, int N_) {
    __shared__ float tile[32][33];
    int l = blockIdx.z;
    int n0 = blockIdx.x * 32, k0 = blockIdx.y * 32;
    const float* s = src + (size_t)l * K_ * N_;
    unsigned short* d = dst + (size_t)l * N_ * K_;
    int tx = threadIdx.x & 31, ty = threadIdx.x >> 5;
#pragma unroll
    for (int i = 0; i < 32; i += 8)
        tile[ty + i][tx] = s[(size_t)(k0 + ty + i) * N_ + n0 + tx];
    __syncthreads();
#pragma unroll
    for (int i = 0; i < 32; i += 8)
        d[(size_t)(n0 + ty + i) * K_ + k0 + tx] = f2b(tile[tx][ty + i]);
}

// ---------------------------------------------------------------------------
// GINE aggregation (vectorized): 128 threads/node, 2 dims/thread via uint.
// zb[n,:] = bf16( hf[n,:] + sum_{e: dst=n} relu(hb[src,:] + ea*ew + eb) )
// ---------------------------------------------------------------------------
__global__ __launch_bounds__(128)
void k_gine_agg(const float* __restrict__ hf, const unsigned short* __restrict__ hb,
                const float* __restrict__ edge_attr,
                const int* __restrict__ srcs, const int* __restrict__ rowptr,
                const int* __restrict__ perm, const float* __restrict__ ew,
                const float* __restrict__ eb, unsigned short* __restrict__ zb) {
    __shared__ int   s_src[64];
    __shared__ float s_ea[64];
    int n = blockIdx.x;
    int t = threadIdx.x;               // 0..127
    int beg = rowptr[n], end = rowptr[n + 1];
    float ew0 = ew[2 * t], ew1 = ew[2 * t + 1];
    float eb0 = eb[2 * t], eb1 = eb[2 * t + 1];
    const unsigned int* hb32 = (const unsigned int*)hb;   // row = 128 uints
    float acc0 = 0.f, acc1 = 0.f;
    for (int c = beg; c < end; c += 64) {
        int cnt = min(64, end - c);
        __syncthreads();
        if (t < cnt) {
            int eid = perm[c + t];
            s_src[t] = srcs[eid];
            s_ea[t]  = edge_attr[eid];
        }
        __syncthreads();
        for (int i = 0; i < cnt; ++i) {
            unsigned int v = hb32[(size_t)s_src[i] * 128 + t];
            float ea = s_ea[i];
            float lo = b2f((unsigned short)(v & 0xffff));
            float hi = b2f((unsigned short)(v >> 16));
            acc0 += fmaxf(lo + ea * ew0 + eb0, 0.f);
            acc1 += fmaxf(hi + ea * ew1 + eb1, 0.f);
        }
    }
    size_t o = (size_t)n * DMODEL + 2 * t;
    float z0 = hf[o] + acc0, z1 = hf[o + 1] + acc1;
    unsigned int pk = (unsigned int)f2b(z0) | ((unsigned int)f2b(z1) << 16);
    *(unsigned int*)&zb[o] = pk;
}

// ---------------------------------------------------------------------------
// bf16 MFMA GEMM (m97 structure): C[M,N] = A[M,K] @ B[K,N]
// ---------------------------------------------------------------------------
template <int MODE, int WF32, int WB16>
__global__ __launch_bounds__(256)
void k_mm(const unsigned short* __restrict__ A, const unsigned short* __restrict__ Bt,
          const float* __restrict__ bias, const float* __restrict__ res,
          const float* __restrict__ add2, const float* __restrict__ g,
          const float* __restrict__ gb, float* __restrict__ Cf,
          unsigned short* __restrict__ Cb, int M, int N, int K) {
    const int BM = 128, BN = 128, BK = 32;
    __shared__ unsigned short As[BM * BK];
    __shared__ unsigned short Bs[BN * BK];

    int t = threadIdx.x;
    int w = t >> 6, l = t & 63;
    int wr = w >> 1, wc = w & 1;
    int bm = blockIdx.y * BM, bn = blockIdx.x * BN;

    f32x4 acc[4][4] = {};

    int rl = l & 15;
    int kc = l >> 4;

    for (int k0 = 0; k0 < K; k0 += BK) {
#pragma unroll
        for (int i = 0; i < 2; ++i) {
            int slot = i * 256 + t;
            int row = slot >> 2, kcc = slot & 3;
            const unsigned short* gp = A + (size_t)(bm + row) * K + k0 + kcc * 8;
            __builtin_amdgcn_global_load_lds(
                (const __attribute__((address_space(1))) void*)gp,
                (__attribute__((address_space(3))) void*)&As[(i * 256 + w * 64) * 8],
                16, 0, 0);
        }
#pragma unroll
        for (int i = 0; i < 2; ++i) {
            int slot = i * 256 + t;
            int row = slot >> 2, kcc = slot & 3;
            const unsigned short* gp = Bt + (size_t)(bn + row) * K + k0 + kcc * 8;
            __builtin_amdgcn_global_load_lds(
                (const __attribute__((address_space(1))) void*)gp,
                (__attribute__((address_space(3))) void*)&Bs[(i * 256 + w * 64) * 8],
                16, 0, 0);
        }
        asm volatile("s_waitcnt vmcnt(0)" ::: "memory");
        __syncthreads();

        bf16x8 av[4], bv[4];
#pragma unroll
        for (int m = 0; m < 4; ++m)
            av[m] = *(const bf16x8*)&As[(wr * 64 + m * 16 + rl) * BK + kc * 8];
#pragma unroll
        for (int n = 0; n < 4; ++n)
            bv[n] = *(const bf16x8*)&Bs[(wc * 64 + n * 16 + rl) * BK + kc * 8];
#pragma unroll
        for (int m = 0; m < 4; ++m)
#pragma unroll
            for (int n = 0; n < 4; ++n)
                acc[m][n] = __builtin_amdgcn_mfma_f32_16x16x32_bf16(av[m], bv[n], acc[m][n], 0, 0, 0);
        __syncthreads();
    }

    int rh = l >> 4;
#pragma unroll
    for (int n = 0; n < 4; ++n) {
        int col = bn + wc * 64 + n * 16 + rl;
        float bv_ = bias[col];
        float gs = 0.f, gbv = 0.f;
        if (MODE >= 2) { gs = g[col] * bn_scale_c(); gbv = gb[col]; }
#pragma unroll
        for (int m = 0; m < 4; ++m) {
#pragma unroll
            for (int j = 0; j < 4; ++j) {
                int row = bm + wr * 64 + m * 16 + rh * 4 + j;
                size_t idx = (size_t)row * N + col;
                float v = acc[m][n][j] + bv_;
                if (MODE == 1) v = fmaxf(v, 0.f);
                if (MODE >= 2) v = (v + res[idx]) * gs + gbv;
                if (MODE == 3) v += add2[idx];
                if (WF32) Cf[idx] = v;
                if (WB16) Cb[idx] = f2b(v);
            }
        }
    }
}

// ---------------------------------------------------------------------------
// MFMA attention. Block = (graph b, head h). 4 waves x 64 q-rows.
// K in LDS [256][40] bf16 (B-operand layout, k=dhead).
// V^T in LDS [32][264] bf16 (B-operand layout for PV, k=key).
// P per-wave [16][264] bf16. Single-pass softmax (all 256 scores in regs).
// ---------------------------------------------------------------------------
#define KP 40
#define VP 264
__global__ __launch_bounds__(256)
void k_attn(const unsigned short* __restrict__ qkv, unsigned short* __restrict__ o) {
    __shared__ unsigned short lds[10240 + 8448 + 16896]; // Ks | Vt | Ps (71168 B)
    unsigned short* Ks = lds;              // [256][40]
    unsigned short* Vt = lds + 10240;      // [32][264]
    unsigned short* Ps = lds + 10240 + 8448; // 4 x [16][264]

    int bh = blockIdx.x;
    int b = bh >> 3, h = bh & 7;
    int t = threadIdx.x;
    int w = t >> 6, l = t & 63;
    int rl = l & 15, kc = l >> 4;          // kc in [0,4)
    const float scale = 0.17677669529663687f; // 1/sqrt(32)

    const unsigned short* base = qkv + (size_t)b * NNODE * (3 * DMODEL);

    // ---- stage K and V^T ----
    {
        int j = t;   // key row 0..255
        const unsigned short* row = base + (size_t)j * (3 * DMODEL);
#pragma unroll
        for (int c = 0; c < 4; ++c) {
            bf16x8 kvv = *(const bf16x8*)(row + DMODEL + h * DHEAD + c * 8);
            *(bf16x8*)&Ks[j * KP + c * 8] = kvv;
        }
#pragma unroll
        for (int c = 0; c < 4; ++c) {
            bf16x8 vv = *(const bf16x8*)(row + 2 * DMODEL + h * DHEAD + c * 8);
#pragma unroll
            for (int e = 0; e < 8; ++e)
                Vt[(c * 8 + e) * VP + j] = (unsigned short)vv[e];
        }
    }

    // ---- Q fragments (A-operand): lane: Q[q0+rl, kc*8..+7] ----
    bf16x8 av[4];
#pragma unroll
    for (int m = 0; m < 4; ++m) {
        int q = w * 64 + m * 16 + rl;
        av[m] = *(const bf16x8*)(base + (size_t)q * (3 * DMODEL) + h * DHEAD + kc * 8);
    }
    __syncthreads();

    unsigned short* Pw = Ps + w * 16 * VP;
    f32x4 zero = {0.f, 0.f, 0.f, 0.f};

#pragma unroll 1
    for (int m = 0; m < 4; ++m) {
        // ---- S = Q K^T : 16 col-frags ----
        f32x4 s[16];
#pragma unroll
        for (int n = 0; n < 16; ++n) {
            bf16x8 kv = *(const bf16x8*)&Ks[(n * 16 + rl) * KP + kc * 8];
            s[n] = __builtin_amdgcn_mfma_f32_16x16x32_bf16(av[m], kv, zero, 0, 0, 0);
        }
        // ---- softmax over 256 keys (cols), rows = (l>>4)*4+j ----
        float mj[4] = {-1e30f, -1e30f, -1e30f, -1e30f};
#pragma unroll
        for (int n = 0; n < 16; ++n)
#pragma unroll
            for (int j = 0; j < 4; ++j) mj[j] = fmaxf(mj[j], s[n][j]);
#pragma unroll
        for (int off = 1; off < 16; off <<= 1)
#pragma unroll
            for (int j = 0; j < 4; ++j) mj[j] = fmaxf(mj[j], __shfl_xor(mj[j], off));
        float sumj[4] = {0.f, 0.f, 0.f, 0.f};
#pragma unroll
        for (int n = 0; n < 16; ++n) {
#pragma unroll
            for (int j = 0; j < 4; ++j) {
                float p = __expf((s[n][j] - mj[j]) * scale);
                sumj[j] += p;
                Pw[(kc * 4 + j) * VP + n * 16 + rl] = f2b(p);
            }
        }
#pragma unroll
        for (int off = 1; off < 16; off <<= 1)
#pragma unroll
            for (int j = 0; j < 4; ++j) sumj[j] += __shfl_xor(sumj[j], off);

        // ---- O = P V : k = 256 keys in 8 steps ----
        f32x4 o0 = zero, o1 = zero;
#pragma unroll
        for (int ks = 0; ks < 8; ++ks) {
            bf16x8 pa = *(const bf16x8*)&Pw[rl * VP + ks * 32 + kc * 8];
            bf16x8 v0 = *(const bf16x8*)&Vt[rl * VP + ks * 32 + kc * 8];
            bf16x8 v1 = *(const bf16x8*)&Vt[(16 + rl) * VP + ks * 32 + kc * 8];
            o0 = __builtin_amdgcn_mfma_f32_16x16x32_bf16(pa, v0, o0, 0, 0, 0);
            o1 = __builtin_amdgcn_mfma_f32_16x16x32_bf16(pa, v1, o1, 0, 0, 0);
        }
        // ---- write O (normalized) ----
#pragma unroll
        for (int j = 0; j < 4; ++j) {
            float inv = 1.f / sumj[j];
            int q = w * 64 + m * 16 + kc * 4 + j;
            unsigned short* orow = o + ((size_t)b * NNODE + q) * DMODEL + h * DHEAD;
            orow[rl]      = f2b(o0[j] * inv);
            orow[16 + rl] = f2b(o1[j] * inv);
        }
    }
}

// ---------------------------------------------------------------------------
extern "C" void kernel_launch(void* const* d_in, const int* in_sizes, int n_in,
                              void* d_out, int out_size, void* d_ws, size_t ws_size,
                              hipStream_t stream) {
    const float* x          = (const float*)d_in[0];
    const float* edge_attr  = (const float*)d_in[1];
    const float* node_w     = (const float*)d_in[2];
    const float* node_b     = (const float*)d_in[3];
    const float* edge_w     = (const float*)d_in[4];
    const float* edge_b     = (const float*)d_in[5];
    const float* gine_w1    = (const float*)d_in[6];
    const float* gine_b1    = (const float*)d_in[7];
    const float* gine_w2    = (const float*)d_in[8];
    const float* gine_b2    = (const float*)d_in[9];
    const float* attn_in_w  = (const float*)d_in[10];
    const float* attn_in_b  = (const float*)d_in[11];
    const float* attn_out_w = (const float*)d_in[12];
    const float* attn_out_b = (const float*)d_in[13];
    const float* mlp_w1     = (const float*)d_in[14];
    const float* mlp_b1     = (const float*)d_in[15];
    const float* mlp_w2     = (const float*)d_in[16];
    const float* mlp_b2     = (const float*)d_in[17];
    const float* bn1_g      = (const float*)d_in[18];
    const float* bn1_b      = (const float*)d_in[19];
    const float* bn2_g      = (const float*)d_in[20];
    const float* bn2_b      = (const float*)d_in[21];
    const float* bn3_g      = (const float*)d_in[22];
    const float* bn3_b      = (const float*)d_in[23];
    const int*   edge_index = (const int*)d_in[24];

    const int* srcp = edge_index;
    const int* dstp = edge_index + EDGES;

    float* out = (float*)d_out;
    char*  ws  = (char*)d_ws;

    // ---- workspace layout ----
    size_t off = 0;
    float* hf    = (float*)(ws + off); off += (size_t)NTOT * DMODEL * 4;
    float* h1f   = (float*)(ws + off); off += (size_t)NTOT * DMODEL * 4;
    float* combf = (float*)(ws + off); off += (size_t)NTOT * DMODEL * 4;
    unsigned short* hb   = (unsigned short*)(ws + off); off += (size_t)NTOT * DMODEL * 2;
    unsigned short* bufA = (unsigned short*)(ws + off); off += (size_t)NTOT * 3 * DMODEL * 2;
    unsigned short* bufB = (unsigned short*)(ws + off); off += (size_t)NTOT * 2 * DMODEL * 2;
    unsigned short* xb   = (unsigned short*)(ws + off); off += (size_t)NTOT * DIN * 2;
    unsigned short* w_node = (unsigned short*)(ws + off); off += (size_t)DMODEL * DIN * 2;
    unsigned short* w_g1   = (unsigned short*)(ws + off); off += (size_t)NLAYER * DMODEL * DMODEL * 2;
    unsigned short* w_g2   = (unsigned short*)(ws + off); off += (size_t)NLAYER * DMODEL * DMODEL * 2;
    unsigned short* w_ai   = (unsigned short*)(ws + off); off += (size_t)NLAYER * 3 * DMODEL * DMODEL * 2;
    unsigned short* w_ao   = (unsigned short*)(ws + off); off += (size_t)NLAYER * DMODEL * DMODEL * 2;
    unsigned short* w_m1   = (unsigned short*)(ws + off); off += (size_t)NLAYER * 2 * DMODEL * DMODEL * 2;
    unsigned short* w_m2   = (unsigned short*)(ws + off); off += (size_t)NLAYER * 2 * DMODEL * DMODEL * 2;
    int* rowptr = (int*)(ws + off); off += ((size_t)NTOT + 4) * 4;
    int* perm   = (int*)(ws + off); off += (size_t)EDGES * 4;
    int* cnt    = (int*)(ws + off); off += (size_t)NTOT * 4;
    int* bsum   = (int*)(ws + off); off += 128 * 4;
    (void)ws_size; (void)in_sizes; (void)n_in; (void)out_size;

    // ---- CSR build ----
    hipMemsetAsync(cnt, 0, (size_t)NTOT * 4, stream);
    k_hist<<<EDGES / 256, 256, 0, stream>>>(dstp, cnt);
    k_block_sum<<<NTOT / 256, 256, 0, stream>>>(cnt, bsum);
    k_scan_bsum<<<1, 64, 0, stream>>>(bsum, NTOT / 256);
    k_scan_chunks<<<NTOT / 256, 256, 0, stream>>>(cnt, bsum, rowptr);
    hipMemsetAsync(cnt, 0, (size_t)NTOT * 4, stream);
    k_fill_perm<<<EDGES / 256, 256, 0, stream>>>(dstp, rowptr, cnt, perm);

    // ---- weight & input conversion ----
    k_f2b<<<NTOT * DIN / 4 / 256, 256, 0, stream>>>(x, xb, NTOT * DIN);
    k_convT<<<dim3(DMODEL / 32, DIN / 32, 1), 256, 0, stream>>>(node_w, w_node, DIN, DMODEL);
    k_convT<<<dim3(DMODEL / 32, DMODEL / 32, NLAYER), 256, 0, stream>>>(gine_w1, w_g1, DMODEL, DMODEL);
    k_convT<<<dim3(DMODEL / 32, DMODEL / 32, NLAYER), 256, 0, stream>>>(gine_w2, w_g2, DMODEL, DMODEL);
    k_convT<<<dim3(3 * DMODEL / 32, DMODEL / 32, NLAYER), 256, 0, stream>>>(attn_in_w, w_ai, DMODEL, 3 * DMODEL);
    k_convT<<<dim3(DMODEL / 32, DMODEL / 32, NLAYER), 256, 0, stream>>>(attn_out_w, w_ao, DMODEL, DMODEL);
    k_convT<<<dim3(2 * DMODEL / 32, DMODEL / 32, NLAYER), 256, 0, stream>>>(mlp_w1, w_m1, DMODEL, 2 * DMODEL);
    k_convT<<<dim3(DMODEL / 32, 2 * DMODEL / 32, NLAYER), 256, 0, stream>>>(mlp_w2, w_m2, 2 * DMODEL, DMODEL);

    // ---- encoder ----
    k_mm<0, 1, 1><<<dim3(DMODEL / 128, NTOT / 128), 256, 0, stream>>>(
        xb, w_node, node_b, nullptr, nullptr, nullptr, nullptr, hf, hb, NTOT, DMODEL, DIN);

    for (int l = 0; l < NLAYER; ++l) {
        const unsigned short* g1 = w_g1 + (size_t)l * DMODEL * DMODEL;
        const unsigned short* g2 = w_g2 + (size_t)l * DMODEL * DMODEL;
        const unsigned short* ai = w_ai + (size_t)l * 3 * DMODEL * DMODEL;
        const unsigned short* ao = w_ao + (size_t)l * DMODEL * DMODEL;
        const unsigned short* m1 = w_m1 + (size_t)l * 2 * DMODEL * DMODEL;
        const unsigned short* m2 = w_m2 + (size_t)l * 2 * DMODEL * DMODEL;

        unsigned short* zb   = bufA;
        unsigned short* hidb = bufB;
        unsigned short* qkvb = bufA;
        unsigned short* ob   = bufB;
        unsigned short* cmbb = bufA;
        unsigned short* h5b  = bufB;

        k_gine_agg<<<NTOT, 128, 0, stream>>>(hf, hb, edge_attr, srcp, rowptr, perm,
                                             edge_w, edge_b, zb);
        k_mm<1, 0, 1><<<dim3(2, NTOT / 128), 256, 0, stream>>>(
            zb, g1, gine_b1 + (size_t)l * DMODEL, nullptr, nullptr, nullptr, nullptr,
            nullptr, hidb, NTOT, DMODEL, DMODEL);
        k_mm<2, 1, 0><<<dim3(2, NTOT / 128), 256, 0, stream>>>(
            hidb, g2, gine_b2 + (size_t)l * DMODEL, hf, nullptr,
            bn1_g + (size_t)l * DMODEL, bn1_b + (size_t)l * DMODEL,
            h1f, nullptr, NTOT, DMODEL, DMODEL);

        k_mm<0, 0, 1><<<dim3(6, NTOT / 128), 256, 0, stream>>>(
            hb, ai, attn_in_b + (size_t)l * 3 * DMODEL, nullptr, nullptr, nullptr, nullptr,
            nullptr, qkvb, NTOT, 3 * DMODEL, DMODEL);
        k_attn<<<BGRAPH * NHEAD, 256, 0, stream>>>(qkvb, ob);
        k_mm<3, 1, 1><<<dim3(2, NTOT / 128), 256, 0, stream>>>(
            ob, ao, attn_out_b + (size_t)l * DMODEL, hf, h1f,
            bn2_g + (size_t)l * DMODEL, bn2_b + (size_t)l * DMODEL,
            combf, cmbb, NTOT, DMODEL, DMODEL);

        k_mm<1, 0, 1><<<dim3(4, NTOT / 128), 256, 0, stream>>>(
            cmbb, m1, mlp_b1 + (size_t)l * 2 * DMODEL, nullptr, nullptr, nullptr, nullptr,
            nullptr, h5b, NTOT, 2 * DMODEL, DMODEL);
        float* dest = (l == NLAYER - 1) ? out : hf;
        k_mm<2, 1, 1><<<dim3(2, NTOT / 128), 256, 0, stream>>>(
            h5b, m2, mlp_b2 + (size_t)l * DMODEL, combf, nullptr,
            bn3_g + (size_t)l * DMODEL, bn3_b + (size_t)l * DMODEL,
            dest, hb, NTOT, DMODEL, 2 * DMODEL);
    }
}

// Round 4
// 1247.160 us; speedup vs baseline: 2.9292x; 1.0415x over previous
//
#include <hip/hip_runtime.h>
#include <math.h>

#define NTOT   32768
#define DMODEL 256
#define EDGES  1048576
#define BGRAPH 128
#define NNODE  256
#define NHEAD  8
#define DHEAD  32
#define NLAYER 4
#define DIN    64

typedef short bf16x8 __attribute__((ext_vector_type(8)));
typedef float f32x4  __attribute__((ext_vector_type(4)));

__device__ __forceinline__ float bn_scale_c() { return 0.9999950000374997f; } // 1/sqrt(1+1e-5)

__device__ __forceinline__ unsigned short f2b(float f) {
    union { float f; unsigned int u; } v; v.f = f;
    unsigned int r = v.u + 0x7FFFu + ((v.u >> 16) & 1u);  // RNE
    return (unsigned short)(r >> 16);
}
__device__ __forceinline__ float b2f(unsigned short u) {
    union { unsigned int u; float f; } v; v.u = ((unsigned int)u) << 16;
    return v.f;
}

// ---------------------------------------------------------------------------
// CSR build (dst-indexed)
// ---------------------------------------------------------------------------
__global__ void k_hist(const int* __restrict__ dst, int* __restrict__ cnt) {
    int e = blockIdx.x * 256 + threadIdx.x;
    if (e < EDGES) atomicAdd(&cnt[dst[e]], 1);
}

__global__ void k_block_sum(const int* __restrict__ cnt, int* __restrict__ bsum) {
    __shared__ int s[256];
    int t = threadIdx.x;
    s[t] = cnt[blockIdx.x * 256 + t];
    __syncthreads();
    for (int o = 128; o > 0; o >>= 1) {
        if (t < o) s[t] += s[t + o];
        __syncthreads();
    }
    if (t == 0) bsum[blockIdx.x] = s[0];
}

__global__ void k_scan_bsum(int* __restrict__ bsum, int nb) {
    if (threadIdx.x == 0) {
        int run = 0;
        for (int i = 0; i < nb; ++i) { int v = bsum[i]; bsum[i] = run; run += v; }
    }
}

__global__ void k_scan_chunks(const int* __restrict__ cnt, const int* __restrict__ bsum,
                              int* __restrict__ rowptr) {
    __shared__ int s[256];
    int t = threadIdx.x;
    int gid = blockIdx.x * 256 + t;
    int v = cnt[gid];
    s[t] = v;
    __syncthreads();
    for (int o = 1; o < 256; o <<= 1) {
        int add = (t >= o) ? s[t - o] : 0;
        __syncthreads();
        s[t] += add;
        __syncthreads();
    }
    int incl = s[t];
    rowptr[gid] = bsum[blockIdx.x] + incl - v;   // exclusive
    if (gid == NTOT - 1) rowptr[NTOT] = bsum[blockIdx.x] + incl;
}

__global__ void k_fill_perm(const int* __restrict__ dst, const int* __restrict__ rowptr,
                            int* __restrict__ cursor, int* __restrict__ perm) {
    int e = blockIdx.x * 256 + threadIdx.x;
    if (e >= EDGES) return;
    int d = dst[e];
    int pos = rowptr[d] + atomicAdd(&cursor[d], 1);
    perm[pos] = e;
}

// ---------------------------------------------------------------------------
// fp32 -> bf16 elementwise (n % 4 == 0)
// ---------------------------------------------------------------------------
__global__ void k_f2b(const float* __restrict__ s, unsigned short* __restrict__ d, int n) {
    int i = (blockIdx.x * 256 + threadIdx.x) * 4;
    if (i >= n) return;
    float4 v = *(const float4*)(s + i);
    d[i + 0] = f2b(v.x); d[i + 1] = f2b(v.y); d[i + 2] = f2b(v.z); d[i + 3] = f2b(v.w);
}

// ---------------------------------------------------------------------------
// Weight convert + transpose: src[l][k][n] (fp32) -> dst[l][n][k] (bf16)
// ---------------------------------------------------------------------------
__global__ __launch_bounds__(256)
void k_convT(const float* __restrict__ src, unsigned short* __restrict__ dst, int K_, int N_) {
    __shared__ float tile[32][33];
    int l = blockIdx.z;
    int n0 = blockIdx.x * 32, k0 = blockIdx.y * 32;
    const float* s = src + (size_t)l * K_ * N_;
    unsigned short* d = dst + (size_t)l * N_ * K_;
    int tx = threadIdx.x & 31, ty = threadIdx.x >> 5;
#pragma unroll
    for (int i = 0; i < 32; i += 8)
        tile[ty + i][tx] = s[(size_t)(k0 + ty + i) * N_ + n0 + tx];
    __syncthreads();
#pragma unroll
    for (int i = 0; i < 32; i += 8)
        d[(size_t)(n0 + ty + i) * K_ + k0 + tx] = f2b(tile[tx][ty + i]);
}

// ---------------------------------------------------------------------------
// GINE aggregation (vectorized): 128 threads/node, 2 dims/thread via uint.
// ---------------------------------------------------------------------------
__global__ __launch_bounds__(128)
void k_gine_agg(const float* __restrict__ hf, const unsigned short* __restrict__ hb,
                const float* __restrict__ edge_attr,
                const int* __restrict__ srcs, const int* __restrict__ rowptr,
                const int* __restrict__ perm, const float* __restrict__ ew,
                const float* __restrict__ eb, unsigned short* __restrict__ zb) {
    __shared__ int   s_src[64];
    __shared__ float s_ea[64];
    int n = blockIdx.x;
    int t = threadIdx.x;               // 0..127
    int beg = rowptr[n], end = rowptr[n + 1];
    float ew0 = ew[2 * t], ew1 = ew[2 * t + 1];
    float eb0 = eb[2 * t], eb1 = eb[2 * t + 1];
    const unsigned int* hb32 = (const unsigned int*)hb;   // row = 128 uints
    float acc0 = 0.f, acc1 = 0.f;
    for (int c = beg; c < end; c += 64) {
        int cnt = min(64, end - c);
        __syncthreads();
        if (t < cnt) {
            int eid = perm[c + t];
            s_src[t] = srcs[eid];
            s_ea[t]  = edge_attr[eid];
        }
        __syncthreads();
        for (int i = 0; i < cnt; ++i) {
            unsigned int v = hb32[(size_t)s_src[i] * 128 + t];
            float ea = s_ea[i];
            float lo = b2f((unsigned short)(v & 0xffff));
            float hi = b2f((unsigned short)(v >> 16));
            acc0 += fmaxf(lo + ea * ew0 + eb0, 0.f);
            acc1 += fmaxf(hi + ea * ew1 + eb1, 0.f);
        }
    }
    size_t o = (size_t)n * DMODEL + 2 * t;
    float z0 = hf[o] + acc0, z1 = hf[o + 1] + acc1;
    unsigned int pk = (unsigned int)f2b(z0) | ((unsigned int)f2b(z1) << 16);
    *(unsigned int*)&zb[o] = pk;
}

// ---------------------------------------------------------------------------
// bf16 MFMA GEMM (m97 structure): C[M,N] = A[M,K] @ B[K,N]
// ---------------------------------------------------------------------------
template <int MODE, int WF32, int WB16>
__global__ __launch_bounds__(256)
void k_mm(const unsigned short* __restrict__ A, const unsigned short* __restrict__ Bt,
          const float* __restrict__ bias, const float* __restrict__ res,
          const float* __restrict__ add2, const float* __restrict__ g,
          const float* __restrict__ gb, float* __restrict__ Cf,
          unsigned short* __restrict__ Cb, int M, int N, int K) {
    const int BM = 128, BN = 128, BK = 32;
    __shared__ unsigned short As[BM * BK];
    __shared__ unsigned short Bs[BN * BK];

    int t = threadIdx.x;
    int w = t >> 6, l = t & 63;
    int wr = w >> 1, wc = w & 1;
    int bm = blockIdx.y * BM, bn = blockIdx.x * BN;

    f32x4 acc[4][4] = {};

    int rl = l & 15;
    int kc = l >> 4;

    for (int k0 = 0; k0 < K; k0 += BK) {
#pragma unroll
        for (int i = 0; i < 2; ++i) {
            int slot = i * 256 + t;
            int row = slot >> 2, kcc = slot & 3;
            const unsigned short* gp = A + (size_t)(bm + row) * K + k0 + kcc * 8;
            __builtin_amdgcn_global_load_lds(
                (const __attribute__((address_space(1))) void*)gp,
                (__attribute__((address_space(3))) void*)&As[(i * 256 + w * 64) * 8],
                16, 0, 0);
        }
#pragma unroll
        for (int i = 0; i < 2; ++i) {
            int slot = i * 256 + t;
            int row = slot >> 2, kcc = slot & 3;
            const unsigned short* gp = Bt + (size_t)(bn + row) * K + k0 + kcc * 8;
            __builtin_amdgcn_global_load_lds(
                (const __attribute__((address_space(1))) void*)gp,
                (__attribute__((address_space(3))) void*)&Bs[(i * 256 + w * 64) * 8],
                16, 0, 0);
        }
        asm volatile("s_waitcnt vmcnt(0)" ::: "memory");
        __syncthreads();

        bf16x8 av[4], bv[4];
#pragma unroll
        for (int m = 0; m < 4; ++m)
            av[m] = *(const bf16x8*)&As[(wr * 64 + m * 16 + rl) * BK + kc * 8];
#pragma unroll
        for (int n = 0; n < 4; ++n)
            bv[n] = *(const bf16x8*)&Bs[(wc * 64 + n * 16 + rl) * BK + kc * 8];
#pragma unroll
        for (int m = 0; m < 4; ++m)
#pragma unroll
            for (int n = 0; n < 4; ++n)
                acc[m][n] = __builtin_amdgcn_mfma_f32_16x16x32_bf16(av[m], bv[n], acc[m][n], 0, 0, 0);
        __syncthreads();
    }

    int rh = l >> 4;
#pragma unroll
    for (int n = 0; n < 4; ++n) {
        int col = bn + wc * 64 + n * 16 + rl;
        float bv_ = bias[col];
        float gs = 0.f, gbv = 0.f;
        if (MODE >= 2) { gs = g[col] * bn_scale_c(); gbv = gb[col]; }
#pragma unroll
        for (int m = 0; m < 4; ++m) {
#pragma unroll
            for (int j = 0; j < 4; ++j) {
                int row = bm + wr * 64 + m * 16 + rh * 4 + j;
                size_t idx = (size_t)row * N + col;
                float v = acc[m][n][j] + bv_;
                if (MODE == 1) v = fmaxf(v, 0.f);
                if (MODE >= 2) v = (v + res[idx]) * gs + gbv;
                if (MODE == 3) v += add2[idx];
                if (WF32) Cf[idx] = v;
                if (WB16) Cb[idx] = f2b(v);
            }
        }
    }
}

// ---------------------------------------------------------------------------
// MFMA attention, swapped-operand QK^T. Block = (graph b, head h). 4 waves x
// 64 q-rows. S = mfma(A=K_tile, B=Q) -> lane (rl,kc) holds
// S[q=rl][key=n*16+kc*4+j]: 4 consecutive keys -> packed b64 P stores,
// 2-shuffle softmax reductions. PV unchanged (contiguous b128 frag reads).
// ---------------------------------------------------------------------------
#define KP 40
#define VP 264
__global__ __launch_bounds__(256)
void k_attn(const unsigned short* __restrict__ qkv, unsigned short* __restrict__ o) {
    __shared__ unsigned short lds[10240 + 8448 + 16896]; // Ks | Vt | Ps (71168 B)
    unsigned short* Ks = lds;                 // [256][40]
    unsigned short* Vt = lds + 10240;         // [32][264]
    unsigned short* Ps = lds + 10240 + 8448;  // 4 x [16][264]

    int bh = blockIdx.x;
    int b = bh >> 3, h = bh & 7;
    int t = threadIdx.x;
    int w = t >> 6, l = t & 63;
    int rl = l & 15, kc = l >> 4;             // kc in [0,4)
    const float scale = 0.17677669529663687f; // 1/sqrt(32)

    const unsigned short* base = qkv + (size_t)b * NNODE * (3 * DMODEL);

    // ---- stage K: thread t = key row ----
    {
        const unsigned short* row = base + (size_t)t * (3 * DMODEL);
#pragma unroll
        for (int c = 0; c < 4; ++c) {
            bf16x8 kvv = *(const bf16x8*)(row + DMODEL + h * DHEAD + c * 8);
            *(bf16x8*)&Ks[t * KP + c * 8] = kvv;
        }
    }
    // ---- stage V^T: thread t -> keys k0..k0+3, dims d0..d0+7, b64 packed ----
    {
        int k0 = (t & 63) * 4, d0 = (t >> 6) * 8;
        bf16x8 vr[4];
#pragma unroll
        for (int i = 0; i < 4; ++i)
            vr[i] = *(const bf16x8*)(base + (size_t)(k0 + i) * (3 * DMODEL) + 2 * DMODEL + h * DHEAD + d0);
#pragma unroll
        for (int d = 0; d < 8; ++d) {
            ushort4 pk;
            pk.x = (unsigned short)vr[0][d];
            pk.y = (unsigned short)vr[1][d];
            pk.z = (unsigned short)vr[2][d];
            pk.w = (unsigned short)vr[3][d];
            *(ushort4*)&Vt[(d0 + d) * VP + k0] = pk;
        }
    }

    // ---- Q fragments (B-operand): lane (rl,kc): Q[qb+rl][kc*8..+7] ----
    bf16x8 qv[4];
#pragma unroll
    for (int m = 0; m < 4; ++m) {
        int q = w * 64 + m * 16 + rl;
        qv[m] = *(const bf16x8*)(base + (size_t)q * (3 * DMODEL) + h * DHEAD + kc * 8);
    }
    __syncthreads();

    unsigned short* Pw = Ps + w * 16 * VP;
    f32x4 zero = {0.f, 0.f, 0.f, 0.f};

#pragma unroll 1
    for (int m = 0; m < 4; ++m) {
        // ---- S^T tiles: s[n] = mfma(K_tile_n, Q) ----
        f32x4 s[16];
#pragma unroll
        for (int n = 0; n < 16; ++n) {
            bf16x8 kv = *(const bf16x8*)&Ks[(n * 16 + rl) * KP + kc * 8];
            s[n] = __builtin_amdgcn_mfma_f32_16x16x32_bf16(kv, qv[m], zero, 0, 0, 0);
        }
        // ---- softmax row q=rl (lane-local over n,j; reduce across kc) ----
        float mv = -1e30f;
#pragma unroll
        for (int n = 0; n < 16; ++n)
#pragma unroll
            for (int j = 0; j < 4; ++j) mv = fmaxf(mv, s[n][j]);
        mv = fmaxf(mv, __shfl_xor(mv, 16));
        mv = fmaxf(mv, __shfl_xor(mv, 32));
        float sumv = 0.f;
#pragma unroll
        for (int n = 0; n < 16; ++n) {
            float p0 = __expf((s[n][0] - mv) * scale);
            float p1 = __expf((s[n][1] - mv) * scale);
            float p2 = __expf((s[n][2] - mv) * scale);
            float p3 = __expf((s[n][3] - mv) * scale);
            sumv += (p0 + p1) + (p2 + p3);
            unsigned int lo, hi;
            asm("v_cvt_pk_bf16_f32 %0, %1, %2" : "=v"(lo) : "v"(p0), "v"(p1));
            asm("v_cvt_pk_bf16_f32 %0, %1, %2" : "=v"(hi) : "v"(p2), "v"(p3));
            uint2 pk; pk.x = lo; pk.y = hi;
            *(uint2*)&Pw[rl * VP + n * 16 + kc * 4] = pk;
        }
        sumv += __shfl_xor(sumv, 16);
        sumv += __shfl_xor(sumv, 32);

        // ---- O = P V : k = 256 keys in 8 steps ----
        f32x4 o0 = zero, o1 = zero;
#pragma unroll
        for (int ks = 0; ks < 8; ++ks) {
            bf16x8 pa = *(const bf16x8*)&Pw[rl * VP + ks * 32 + kc * 8];
            bf16x8 v0 = *(const bf16x8*)&Vt[rl * VP + ks * 32 + kc * 8];
            bf16x8 v1 = *(const bf16x8*)&Vt[(16 + rl) * VP + ks * 32 + kc * 8];
            o0 = __builtin_amdgcn_mfma_f32_16x16x32_bf16(pa, v0, o0, 0, 0, 0);
            o1 = __builtin_amdgcn_mfma_f32_16x16x32_bf16(pa, v1, o1, 0, 0, 0);
        }
        // ---- write O (normalized); row sums live at lane rl=q, fetch via shfl ----
#pragma unroll
        for (int j = 0; j < 4; ++j) {
            float sj = __shfl(sumv, kc * 4 + j);
            float inv = 1.f / sj;
            int q = w * 64 + m * 16 + kc * 4 + j;
            unsigned short* orow = o + ((size_t)b * NNODE + q) * DMODEL + h * DHEAD;
            orow[rl]      = f2b(o0[j] * inv);
            orow[16 + rl] = f2b(o1[j] * inv);
        }
    }
}

// ---------------------------------------------------------------------------
extern "C" void kernel_launch(void* const* d_in, const int* in_sizes, int n_in,
                              void* d_out, int out_size, void* d_ws, size_t ws_size,
                              hipStream_t stream) {
    const float* x          = (const float*)d_in[0];
    const float* edge_attr  = (const float*)d_in[1];
    const float* node_w     = (const float*)d_in[2];
    const float* node_b     = (const float*)d_in[3];
    const float* edge_w     = (const float*)d_in[4];
    const float* edge_b     = (const float*)d_in[5];
    const float* gine_w1    = (const float*)d_in[6];
    const float* gine_b1    = (const float*)d_in[7];
    const float* gine_w2    = (const float*)d_in[8];
    const float* gine_b2    = (const float*)d_in[9];
    const float* attn_in_w  = (const float*)d_in[10];
    const float* attn_in_b  = (const float*)d_in[11];
    const float* attn_out_w = (const float*)d_in[12];
    const float* attn_out_b = (const float*)d_in[13];
    const float* mlp_w1     = (const float*)d_in[14];
    const float* mlp_b1     = (const float*)d_in[15];
    const float* mlp_w2     = (const float*)d_in[16];
    const float* mlp_b2     = (const float*)d_in[17];
    const float* bn1_g      = (const float*)d_in[18];
    const float* bn1_b      = (const float*)d_in[19];
    const float* bn2_g      = (const float*)d_in[20];
    const float* bn2_b      = (const float*)d_in[21];
    const float* bn3_g      = (const float*)d_in[22];
    const float* bn3_b      = (const float*)d_in[23];
    const int*   edge_index = (const int*)d_in[24];

    const int* srcp = edge_index;
    const int* dstp = edge_index + EDGES;

    float* out = (float*)d_out;
    char*  ws  = (char*)d_ws;

    // ---- workspace layout ----
    size_t off = 0;
    float* hf    = (float*)(ws + off); off += (size_t)NTOT * DMODEL * 4;
    float* h1f   = (float*)(ws + off); off += (size_t)NTOT * DMODEL * 4;
    float* combf = (float*)(ws + off); off += (size_t)NTOT * DMODEL * 4;
    unsigned short* hb   = (unsigned short*)(ws + off); off += (size_t)NTOT * DMODEL * 2;
    unsigned short* bufA = (unsigned short*)(ws + off); off += (size_t)NTOT * 3 * DMODEL * 2;
    unsigned short* bufB = (unsigned short*)(ws + off); off += (size_t)NTOT * 2 * DMODEL * 2;
    unsigned short* xb   = (unsigned short*)(ws + off); off += (size_t)NTOT * DIN * 2;
    unsigned short* w_node = (unsigned short*)(ws + off); off += (size_t)DMODEL * DIN * 2;
    unsigned short* w_g1   = (unsigned short*)(ws + off); off += (size_t)NLAYER * DMODEL * DMODEL * 2;
    unsigned short* w_g2   = (unsigned short*)(ws + off); off += (size_t)NLAYER * DMODEL * DMODEL * 2;
    unsigned short* w_ai   = (unsigned short*)(ws + off); off += (size_t)NLAYER * 3 * DMODEL * DMODEL * 2;
    unsigned short* w_ao   = (unsigned short*)(ws + off); off += (size_t)NLAYER * DMODEL * DMODEL * 2;
    unsigned short* w_m1   = (unsigned short*)(ws + off); off += (size_t)NLAYER * 2 * DMODEL * DMODEL * 2;
    unsigned short* w_m2   = (unsigned short*)(ws + off); off += (size_t)NLAYER * 2 * DMODEL * DMODEL * 2;
    int* rowptr = (int*)(ws + off); off += ((size_t)NTOT + 4) * 4;
    int* perm   = (int*)(ws + off); off += (size_t)EDGES * 4;
    int* cnt    = (int*)(ws + off); off += (size_t)NTOT * 4;
    int* bsum   = (int*)(ws + off); off += 128 * 4;
    (void)ws_size; (void)in_sizes; (void)n_in; (void)out_size;

    // ---- CSR build ----
    hipMemsetAsync(cnt, 0, (size_t)NTOT * 4, stream);
    k_hist<<<EDGES / 256, 256, 0, stream>>>(dstp, cnt);
    k_block_sum<<<NTOT / 256, 256, 0, stream>>>(cnt, bsum);
    k_scan_bsum<<<1, 64, 0, stream>>>(bsum, NTOT / 256);
    k_scan_chunks<<<NTOT / 256, 256, 0, stream>>>(cnt, bsum, rowptr);
    hipMemsetAsync(cnt, 0, (size_t)NTOT * 4, stream);
    k_fill_perm<<<EDGES / 256, 256, 0, stream>>>(dstp, rowptr, cnt, perm);

    // ---- weight & input conversion ----
    k_f2b<<<NTOT * DIN / 4 / 256, 256, 0, stream>>>(x, xb, NTOT * DIN);
    k_convT<<<dim3(DMODEL / 32, DIN / 32, 1), 256, 0, stream>>>(node_w, w_node, DIN, DMODEL);
    k_convT<<<dim3(DMODEL / 32, DMODEL / 32, NLAYER), 256, 0, stream>>>(gine_w1, w_g1, DMODEL, DMODEL);
    k_convT<<<dim3(DMODEL / 32, DMODEL / 32, NLAYER), 256, 0, stream>>>(gine_w2, w_g2, DMODEL, DMODEL);
    k_convT<<<dim3(3 * DMODEL / 32, DMODEL / 32, NLAYER), 256, 0, stream>>>(attn_in_w, w_ai, DMODEL, 3 * DMODEL);
    k_convT<<<dim3(DMODEL / 32, DMODEL / 32, NLAYER), 256, 0, stream>>>(attn_out_w, w_ao, DMODEL, DMODEL);
    k_convT<<<dim3(2 * DMODEL / 32, DMODEL / 32, NLAYER), 256, 0, stream>>>(mlp_w1, w_m1, DMODEL, 2 * DMODEL);
    k_convT<<<dim3(DMODEL / 32, 2 * DMODEL / 32, NLAYER), 256, 0, stream>>>(mlp_w2, w_m2, 2 * DMODEL, DMODEL);

    // ---- encoder ----
    k_mm<0, 1, 1><<<dim3(DMODEL / 128, NTOT / 128), 256, 0, stream>>>(
        xb, w_node, node_b, nullptr, nullptr, nullptr, nullptr, hf, hb, NTOT, DMODEL, DIN);

    for (int l = 0; l < NLAYER; ++l) {
        const unsigned short* g1 = w_g1 + (size_t)l * DMODEL * DMODEL;
        const unsigned short* g2 = w_g2 + (size_t)l * DMODEL * DMODEL;
        const unsigned short* ai = w_ai + (size_t)l * 3 * DMODEL * DMODEL;
        const unsigned short* ao = w_ao + (size_t)l * DMODEL * DMODEL;
        const unsigned short* m1 = w_m1 + (size_t)l * 2 * DMODEL * DMODEL;
        const unsigned short* m2 = w_m2 + (size_t)l * 2 * DMODEL * DMODEL;

        unsigned short* zb   = bufA;
        unsigned short* hidb = bufB;
        unsigned short* qkvb = bufA;
        unsigned short* ob   = bufB;
        unsigned short* cmbb = bufA;
        unsigned short* h5b  = bufB;

        k_gine_agg<<<NTOT, 128, 0, stream>>>(hf, hb, edge_attr, srcp, rowptr, perm,
                                             edge_w, edge_b, zb);
        k_mm<1, 0, 1><<<dim3(2, NTOT / 128), 256, 0, stream>>>(
            zb, g1, gine_b1 + (size_t)l * DMODEL, nullptr, nullptr, nullptr, nullptr,
            nullptr, hidb, NTOT, DMODEL, DMODEL);
        k_mm<2, 1, 0><<<dim3(2, NTOT / 128), 256, 0, stream>>>(
            hidb, g2, gine_b2 + (size_t)l * DMODEL, hf, nullptr,
            bn1_g + (size_t)l * DMODEL, bn1_b + (size_t)l * DMODEL,
            h1f, nullptr, NTOT, DMODEL, DMODEL);

        k_mm<0, 0, 1><<<dim3(6, NTOT / 128), 256, 0, stream>>>(
            hb, ai, attn_in_b + (size_t)l * 3 * DMODEL, nullptr, nullptr, nullptr, nullptr,
            nullptr, qkvb, NTOT, 3 * DMODEL, DMODEL);
        k_attn<<<BGRAPH * NHEAD, 256, 0, stream>>>(qkvb, ob);
        k_mm<3, 1, 1><<<dim3(2, NTOT / 128), 256, 0, stream>>>(
            ob, ao, attn_out_b + (size_t)l * DMODEL, hf, h1f,
            bn2_g + (size_t)l * DMODEL, bn2_b + (size_t)l * DMODEL,
            combf, cmbb, NTOT, DMODEL, DMODEL);

        k_mm<1, 0, 1><<<dim3(4, NTOT / 128), 256, 0, stream>>>(
            cmbb, m1, mlp_b1 + (size_t)l * 2 * DMODEL, nullptr, nullptr, nullptr, nullptr,
            nullptr, h5b, NTOT, 2 * DMODEL, DMODEL);
        float* dest = (l == NLAYER - 1) ? out : hf;
        k_mm<2, 1, 1><<<dim3(2, NTOT / 128), 256, 0, stream>>>(
            h5b, m2, mlp_b2 + (size_t)l * DMODEL, combf, nullptr,
            bn3_g + (size_t)l * DMODEL, bn3_b + (size_t)l * DMODEL,
            dest, hb, NTOT, DMODEL, 2 * DMODEL);
    }
}